// Round 10
// baseline (579.738 us; speedup 1.0000x reference)
//
#include <hip/hip_runtime.h>

// Problem constants
#define NB 2
#define NC 64
#define HW 200704          // 448*448
#define CHW 12845056       // 64*HW
#define P2 196
#define NCHUNK 1024
#define NCELL 3136         // 56*56
#define WMN 38416          // 196*196

typedef __attribute__((ext_vector_type(8))) short bfrag;   // 8 bf16 (A/B frag)
typedef __attribute__((ext_vector_type(4))) float ffrag;   // 4 f32  (C/D frag)
typedef __attribute__((ext_vector_type(4))) short short4v;
typedef __attribute__((ext_vector_type(4))) float float4v;

#define MFMA16(A,B,C) __builtin_amdgcn_mfma_f32_16x16x32_bf16(A,B,C,0,0,0)

__device__ __forceinline__ short f2bf(float f) {
  unsigned u = __builtin_bit_cast(unsigned, f);
  u = u + 0x7FFFu + ((u >> 16) & 1u);           // RNE
  return (short)(u >> 16);
}

// ---------------- K0: fold proj into V weights (linearity) ------------------
// wtld[o][c] = sum_m pw[o][m]*vw[m][c];  btld[o] = sum_m pw[o][m]*vb[m].
__global__ __launch_bounds__(256) void k0_fold(
    const float* __restrict__ pw, const float* __restrict__ vw,
    const float* __restrict__ vb, float* __restrict__ wtld, float* __restrict__ btld) {
  int t = threadIdx.x;
  if (blockIdx.x == 0) {
    #pragma unroll
    for (int i = 0; i < 16; ++i) {
      int idx = i*256 + t;
      int o = idx >> 6, c = idx & 63;
      float s = 0.f;
      for (int m = 0; m < 64; ++m) s += pw[o*64 + m] * vw[m*64 + c];
      wtld[o*64 + c] = s;
    }
  } else {
    if (t < 64) {
      float s = 0.f;
      for (int m = 0; m < 64; ++m) s += pw[t*64 + m] * vb[m];
      btld[t] = s;
    }
  }
}

// ---------------- K1: groupnorm partial stats + 8x8 avg-pool of x ----------
__global__ __launch_bounds__(64) void k1_stats_pool(
    const float* __restrict__ x, float* __restrict__ xpool, float* __restrict__ partials) {
  int bx = blockIdx.x;
  int batch = bx / (64*56);
  int c = (bx / 56) % 64;
  int pr = bx % 56;
  int l = threadIdx.x;
  const float* xp = x + (size_t)batch*CHW + (size_t)c*HW + pr*8*448;
  float cell = 0.f, s2 = 0.f;
  if (l < 56) {
    #pragma unroll
    for (int r = 0; r < 8; ++r) {
      float4v a = *(const float4v*)(xp + r*448 + l*8);
      float4v b = *(const float4v*)(xp + r*448 + l*8 + 4);
      #pragma unroll
      for (int j = 0; j < 4; ++j) { cell += a[j] + b[j]; s2 += a[j]*a[j] + b[j]*b[j]; }
    }
    xpool[((size_t)batch*64 + c)*NCELL + pr*56 + l] = cell * (1.f/64.f);
  }
  float s1 = (l < 56) ? cell : 0.f;
  #pragma unroll
  for (int m = 1; m < 64; m <<= 1) { s1 += __shfl_xor(s1, m, 64); s2 += __shfl_xor(s2, m, 64); }
  if (l == 0) { partials[bx*2] = s1; partials[bx*2 + 1] = s2; }
}

// ---------------- K1b: reduce 7168 partial pairs -> stats[4] ---------------
__global__ __launch_bounds__(256) void k1b_reduce(
    const float* __restrict__ partials, float* __restrict__ stats) {
  __shared__ float red[2][256];
  int t = threadIdx.x;
  for (int b = 0; b < NB; ++b) {
    float s1 = 0.f, s2 = 0.f;
    for (int i = t; i < 3584; i += 256) {
      s1 += partials[(b*3584 + i)*2];
      s2 += partials[(b*3584 + i)*2 + 1];
    }
    red[0][t] = s1; red[1][t] = s2;
    __syncthreads();
    for (int m = 128; m > 0; m >>= 1) {
      if (t < m) { red[0][t] += red[0][t+m]; red[1][t] += red[1][t+m]; }
      __syncthreads();
    }
    if (t == 0) { stats[b*2] = red[0][0]; stats[b*2+1] = red[1][0]; }
    __syncthreads();
  }
}

// ---------------- K0b: fold GN affine into bf16 weights (per batch) --------
// xn_c = a_c x_c + d_c with a_c = rstd*gnw_c, d_c = gnb_c - mean*a_c.
// W' = W*diag(a) (bf16), b' = b + W.d (fp32). grid NB x 256.
__global__ __launch_bounds__(256) void k0b_foldgn(
    const float* __restrict__ stats, const float* __restrict__ gnw, const float* __restrict__ gnb,
    const float* __restrict__ qw, const float* __restrict__ qb,
    const float* __restrict__ kw, const float* __restrict__ kb,
    const float* __restrict__ vw, const float* __restrict__ vb,
    short* __restrict__ qwb, short* __restrict__ kwb, short* __restrict__ vwb,
    float* __restrict__ qbb, float* __restrict__ kbb, float* __restrict__ vbb) {
  __shared__ float a_s[64], d_s[64];
  int batch = blockIdx.x;
  int t = threadIdx.x;
  float s1 = stats[batch*2], s2 = stats[batch*2+1];
  float mean = s1 * (1.f/CHW);
  float rstd = rsqrtf(s2*(1.f/CHW) - mean*mean + 1e-5f);
  if (t < 64) { float a = rstd*gnw[t]; a_s[t] = a; d_s[t] = gnb[t] - mean*a; }
  __syncthreads();
  const float* Ws[3] = {qw, kw, vw};
  const float* Bs[3] = {qb, kb, vb};
  short* Wo[3] = {qwb, kwb, vwb};
  float* Bo[3] = {qbb, kbb, vbb};
  for (int T = 0; T < 3; ++T) {
    #pragma unroll
    for (int i = 0; i < 16; ++i) {
      int idx = i*256 + t;
      int c = idx & 63;
      Wo[T][batch*4096 + idx] = f2bf(Ws[T][idx] * a_s[c]);
    }
    if (t < 64) {
      float s = Bs[T][t];
      for (int c = 0; c < 64; ++c) s += Ws[T][t*64 + c] * d_s[c];
      Bo[T][batch*64 + t] = s;
    }
  }
}

// ---------------- K2: q,k,v~ = W'.x (GN pre-folded, bf16 weights) ----------
__global__ __launch_bounds__(256) void k2_qkv(
    const float* __restrict__ x,
    const short* __restrict__ qwb, const short* __restrict__ kwb, const short* __restrict__ vwb,
    const float* __restrict__ qbb, const float* __restrict__ kbb, const float* __restrict__ vbb,
    short* __restrict__ qx, short* __restrict__ kx, short* __restrict__ vnat) {
  __shared__ __attribute__((aligned(16))) short xnt[256*72];  // [px][c] bf16, pitch 72
  int bx = blockIdx.x;
  int batch = bx / 784;
  int px0 = (bx % 784) * 256;
  int t = threadIdx.x;
  for (int it = 0; it < 64; it += 4) {
    short4v s;
    #pragma unroll
    for (int r = 0; r < 4; ++r)
      s[r] = f2bf(x[(size_t)batch*CHW + (size_t)(it+r)*HW + px0 + t]);
    *(short4v*)(xnt + t*72 + it) = s;
  }
  __syncthreads();
  int l = t & 63, w = t >> 6, li = l & 15, q_ = l >> 4;
  bfrag bfr[4][2];
  #pragma unroll
  for (int nn = 0; nn < 4; ++nn) {
    int row = (w*4 + nn)*16 + li;
    bfr[nn][0] = *(const bfrag*)(xnt + row*72 + q_*8);
    bfr[nn][1] = *(const bfrag*)(xnt + row*72 + 32 + q_*8);
  }
  const short* Wb[3] = {qwb + batch*4096, kwb + batch*4096, vwb + batch*4096};
  const float* Bb[3] = {qbb + batch*64, kbb + batch*64, vbb + batch*64};
  for (int T = 0; T < 3; ++T) {
    ffrag acc[4][4];
    #pragma unroll
    for (int mt = 0; mt < 4; ++mt) {
      bfrag aw0 = *(const bfrag*)(Wb[T] + (mt*16 + li)*64 + q_*8);
      bfrag aw1 = *(const bfrag*)(Wb[T] + (mt*16 + li)*64 + 32 + q_*8);
      #pragma unroll
      for (int nn = 0; nn < 4; ++nn) {
        ffrag z = {0.f,0.f,0.f,0.f};
        if (T < 2) {            // C[o][px]: col(li)=px, row(q_*4+r)=channel
          z = MFMA16(aw0, bfr[nn][0], z);
          z = MFMA16(aw1, bfr[nn][1], z);
        } else {                // swapped -> C[px][o]: col(li)=channel, rows=px
          z = MFMA16(bfr[nn][0], aw0, z);
          z = MFMA16(bfr[nn][1], aw1, z);
        }
        acc[mt][nn] = z;
      }
    }
    if (T < 2) {
      short* dstb = (T == 0 ? qx : kx) + (size_t)batch*HW*64;
      #pragma unroll
      for (int nn = 0; nn < 4; ++nn) {
        int px = px0 + (w*4 + nn)*16 + li;
        #pragma unroll
        for (int mt = 0; mt < 4; ++mt) {
          float4v bias = *(const float4v*)(Bb[T] + mt*16 + q_*4);
          short4v s;
          #pragma unroll
          for (int r = 0; r < 4; ++r) s[r] = f2bf(acc[mt][nn][r] + bias[r]);
          *(short4v*)(dstb + (size_t)px*64 + mt*16 + q_*4) = s;
        }
      }
    } else {
      #pragma unroll
      for (int mt = 0; mt < 4; ++mt) {
        float bias = Bb[2][mt*16 + li];        // channel = mt*16+li
        short* vrow = vnat + ((size_t)batch*64 + mt*16 + li)*HW + px0;
        #pragma unroll
        for (int nn = 0; nn < 4; ++nn) {
          short4v s;
          #pragma unroll
          for (int r = 0; r < 4; ++r) s[r] = f2bf(acc[mt][nn][r] + bias);
          *(short4v*)(vrow + (w*4 + nn)*16 + q_*4) = s;
        }
      }
    }
  }
}

// ---------------- K2a: pooled qg/kg/vg~ from pool(x) (linearity) -----------
__global__ __launch_bounds__(256) void k2a_pool_qkv(
    const float* __restrict__ xpool, const float* __restrict__ stats,
    const float* __restrict__ gnw, const float* __restrict__ gnb,
    const float* __restrict__ qw, const float* __restrict__ qb,
    const float* __restrict__ kw, const float* __restrict__ kb,
    const float* __restrict__ vw, const float* __restrict__ vb,
    short* __restrict__ qgt, short* __restrict__ kgt, short* __restrict__ vgn) {
  __shared__ float xs[64][64];
  int bx = blockIdx.x;
  int batch = bx / 49;
  int j0 = (bx % 49) * 64;
  int t = threadIdx.x;
  float s1 = stats[batch*2], s2 = stats[batch*2+1];
  float mean = s1 * (1.f/CHW);
  float rstd = rsqrtf(s2*(1.f/CHW) - mean*mean + 1e-5f);
  #pragma unroll
  for (int it = 0; it < 16; ++it) {
    int idx = t + it*256;
    int c = idx >> 6, jl = idx & 63;
    float v = xpool[((size_t)batch*64 + c)*NCELL + j0 + jl];
    xs[c][jl] = (v - mean)*rstd*gnw[c] + gnb[c];
  }
  __syncthreads();
  int jl = t & 63;
  int og = (t >> 6) * 16;
  int j = j0 + jl;
  for (int T = 0; T < 3; ++T) {
    const float* W  = (T==0 ? qw : (T==1 ? kw : vw));
    const float* Bv = (T==0 ? qb : (T==1 ? kb : vb));
    float o16[16];
    #pragma unroll
    for (int oo = 0; oo < 16; ++oo) o16[oo] = Bv[og+oo];
    for (int c = 0; c < 64; ++c) {
      float xv = xs[c][jl];
      #pragma unroll
      for (int oo = 0; oo < 16; ++oo) o16[oo] += W[(og+oo)*64 + c] * xv;
    }
    if (T < 2) {
      short* dst = (T==0 ? qgt : kgt) + ((size_t)batch*NCELL + j)*64 + og;
      #pragma unroll
      for (int oo = 0; oo < 16; oo += 4) {
        short4v s;
        #pragma unroll
        for (int r = 0; r < 4; ++r) s[r] = f2bf(o16[oo+r]);
        *(short4v*)(dst + oo) = s;
      }
    } else {
      #pragma unroll
      for (int oo = 0; oo < 16; ++oo)
        vgn[((size_t)batch*64 + og + oo)*NCELL + j] = f2bf(o16[oo]);
    }
  }
}

// ---------------- K3: wm[p,q] = sum_s qf[s,p] kf[s,q] ----------------------
// R10: 8-way output split (2 m-halves x 4 n-quarters) x 64 slabs = 1024
// blocks (4/CU; R9's 512 was grid-limited at 2/CU, occupancy 18%) + explicit
// register double-buffer prefetch at (chunk,ks)-step granularity: one 6-load
// batch in flight under every MFMA batch. Atomic count UNCHANGED (output
// tiles partitioned -> still 64 slab-adds/element). k re-read 2x, q 4x.
__global__ __launch_bounds__(256) void k3_wm(
    const short* __restrict__ qx, const short* __restrict__ kx, float* __restrict__ wmacc) {
  int bx = blockIdx.x;
  int batch = bx >> 9;
  int rem = bx & 511;
  int slab = rem >> 3;
  int mh = (rem >> 2) & 1;
  int qd = rem & 3;
  int t = threadIdx.x;
  int l = t & 63, w = t >> 6, li = l & 15, q_ = l >> 4;
  // m-tiles (13): half0 -> waves {0-1,2-3,4-5,6}; half1 -> {7-8,9-10,11,12}
  int m0, mcnt;
  if (mh == 0) { m0 = w*2;                    mcnt = (w < 3) ? 2 : 1; }
  else         { m0 = (w < 2) ? 7 + w*2 : 9 + w; mcnt = (w < 2) ? 2 : 1; }
  int nt0 = qd ? 4 + (qd-1)*3 : 0, ncnt = qd ? 3 : 4;
  ffrag acc[2][4];
  #pragma unroll
  for (int i = 0; i < 2; ++i)
    #pragma unroll
    for (int j = 0; j < 4; ++j) acc[i][j] = (ffrag){0.f,0.f,0.f,0.f};
  const short* qbase = qx + ((size_t)batch*HW + (size_t)slab*16*P2)*64;
  const short* kbase = kx + ((size_t)batch*HW + (size_t)slab*16*P2)*64;
  bfrag afA[2], bfA[4], afB[2], bfB[4];
  auto ld = [&](int s, bfrag* af, bfrag* bf) {
    int c8 = s >> 1;
    int koff = (s & 1)*32 + q_*8;
    const short* qc = qbase + (size_t)c8*P2*64;
    const short* kc = kbase + (size_t)c8*P2*64;
    #pragma unroll
    for (int mi = 0; mi < 2; ++mi) if (mi < mcnt)
      af[mi] = *(const bfrag*)(qc + (size_t)((m0+mi)*16 + li)*64 + koff);
    #pragma unroll
    for (int ni = 0; ni < 4; ++ni) if (ni < ncnt)
      bf[ni] = *(const bfrag*)(kc + (size_t)((nt0+ni)*16 + li)*64 + koff);
  };
  auto mm = [&](bfrag* af, bfrag* bf) {
    #pragma unroll
    for (int mi = 0; mi < 2; ++mi) if (mi < mcnt)
      #pragma unroll
      for (int ni = 0; ni < 4; ++ni) if (ni < ncnt)
        acc[mi][ni] = MFMA16(af[mi], bf[ni], acc[mi][ni]);
  };
  // 32 (chunk,ks)-steps, software-pipelined with A/B register buffers
  ld(0, afA, bfA);
  for (int s = 0; s < 32; s += 2) {
    ld(s+1, afB, bfB);
    mm(afA, bfA);
    if (s+2 < 32) ld(s+2, afA, bfA);
    mm(afB, bfB);
  }
  float* wdst = wmacc + (size_t)batch*WMN;
  #pragma unroll
  for (int mi = 0; mi < 2; ++mi) if (mi < mcnt)
    #pragma unroll
    for (int ni = 0; ni < 4; ++ni) if (ni < ncnt) {
      int qcol = (nt0+ni)*16 + li;
      if (qcol < 196)
        #pragma unroll
        for (int r = 0; r < 4; ++r) {
          int prow = (m0+mi)*16 + q_*4 + r;
          if (prow < 196) atomicAdd(wdst + prow*196 + qcol, acc[mi][ni][r]);
        }
    }
}

// ---------------- K4: scale + softmax rows -> P bf16 [208][224] zero-padded -
// 0.75 hp-combine factor folded into P (inv *= 0.75).
__global__ __launch_bounds__(64) void k4_softmax(
    const float* __restrict__ wmacc, short* __restrict__ P) {
  int bx = blockIdx.x;         // NB*208
  int batch = bx / 208;
  int p = bx % 208;
  int l = threadIdx.x;
  short* prow = P + ((size_t)batch*208 + p)*224;
  if (p >= 196) { for (int j = l; j < 224; j += 64) prow[j] = 0; return; }
  const float* src = wmacc + (size_t)batch*WMN + p*196;
  float v[4]; float mx = -1e30f;
  #pragma unroll
  for (int i = 0; i < 4; ++i) {
    int q = l + i*64;
    v[i] = (q < 196) ? src[q]*(1.f/256.f) : -1e30f;
    mx = fmaxf(mx, v[i]);
  }
  #pragma unroll
  for (int m = 1; m < 64; m <<= 1) mx = fmaxf(mx, __shfl_xor(mx, m, 64));
  float s = 0.f;
  #pragma unroll
  for (int i = 0; i < 4; ++i) { v[i] = __expf(v[i] - mx); s += v[i]; }
  #pragma unroll
  for (int m = 1; m < 64; m <<= 1) s += __shfl_xor(s, m, 64);
  float inv = 0.75f / s;        // fold hp combine weight into P
  #pragma unroll
  for (int i = 0; i < 4; ++i) {
    int q = l + i*64;
    if (q < 224) prow[q] = (q < 196) ? f2bf(v[i]*inv) : (short)0;
  }
}

// ---------------- K5: global pooled attention, flash-style ------------------
// grid NB*196: block = one 16-query tile; 4 waves split the 49 KV tiles with
// private (m,l,O), no intra-loop barriers; final 256-thread merge.
__global__ __launch_bounds__(256) void k5_gattn(
    const short* __restrict__ qgt, const short* __restrict__ kgt,
    const short* __restrict__ vgn, float* __restrict__ hgt) {
  __shared__ __attribute__((aligned(16))) short Pl[4][16][72];
  __shared__ __attribute__((aligned(16))) float alph[4][16];
  __shared__ __attribute__((aligned(16))) float Om[4][16][64];
  __shared__ __attribute__((aligned(16))) float ml[4][2][16];
  int bx = blockIdx.x;
  int batch = bx / 196;
  int i0 = (bx % 196) * 16;
  int t = threadIdx.x;
  int w = t >> 6, l = t & 63, li = l & 15, q_ = l >> 4;
  const short* qg = qgt + (size_t)batch*NCELL*64;
  const short* kg = kgt + (size_t)batch*NCELL*64;
  const short* vg = vgn + (size_t)batch*64*NCELL;
  bfrag bq0 = *(const bfrag*)(qg + (size_t)(i0+li)*64 + q_*8);
  bfrag bq1 = *(const bfrag*)(qg + (size_t)(i0+li)*64 + 32 + q_*8);
  float m_run = -1e30f, l_run = 0.f;
  ffrag oa[4];
  #pragma unroll
  for (int i = 0; i < 4; ++i) oa[i] = (ffrag){0.f,0.f,0.f,0.f};
  for (int jt = w; jt < 49; jt += 4) {
    int j0 = jt*64;
    ffrag st[4];
    #pragma unroll
    for (int mt = 0; mt < 4; ++mt) {        // S^T[j,i]: rows j, cols i
      bfrag a0 = *(const bfrag*)(kg + (size_t)(j0 + mt*16 + li)*64 + q_*8);
      bfrag a1 = *(const bfrag*)(kg + (size_t)(j0 + mt*16 + li)*64 + 32 + q_*8);
      ffrag z = {0.f,0.f,0.f,0.f};
      z = MFMA16(a0, bq0, z);
      z = MFMA16(a1, bq1, z);
      st[mt] = z;
    }
    float mx = -1e30f;
    #pragma unroll
    for (int mt = 0; mt < 4; ++mt)
      #pragma unroll
      for (int r = 0; r < 4; ++r) { st[mt][r] *= 0.125f; mx = fmaxf(mx, st[mt][r]); }
    mx = fmaxf(mx, __shfl_xor(mx, 16, 64));
    mx = fmaxf(mx, __shfl_xor(mx, 32, 64));
    float m_new = fmaxf(m_run, mx);
    float alpha = __expf(m_run - m_new);
    float ps = 0.f;
    short4v pk[4];
    #pragma unroll
    for (int mt = 0; mt < 4; ++mt)
      #pragma unroll
      for (int r = 0; r < 4; ++r) { float e = __expf(st[mt][r] - m_new); ps += e; pk[mt][r] = f2bf(e); }
    ps += __shfl_xor(ps, 16, 64);
    ps += __shfl_xor(ps, 32, 64);
    l_run = l_run*alpha + ps;
    m_run = m_new;
    #pragma unroll
    for (int mt = 0; mt < 4; ++mt) *(short4v*)(&Pl[w][li][mt*16 + q_*4]) = pk[mt];
    alph[w][li] = alpha;
    // no barrier: wave reads only its own Pl[w]/alph[w]
    float4v al = *(const float4v*)(&alph[w][q_*4]);
    #pragma unroll
    for (int nt = 0; nt < 4; ++nt)
      #pragma unroll
      for (int r = 0; r < 4; ++r) oa[nt][r] *= al[r];
    #pragma unroll
    for (int ks = 0; ks < 2; ++ks) {
      bfrag a = *(const bfrag*)(&Pl[w][li][ks*32 + q_*8]);
      #pragma unroll
      for (int nt = 0; nt < 4; ++nt) {
        bfrag b = *(const bfrag*)(vg + (size_t)(nt*16 + li)*NCELL + j0 + ks*32 + q_*8);
        oa[nt] = MFMA16(a, b, oa[nt]);
      }
    }
  }
  ml[w][0][li] = m_run;
  ml[w][1][li] = l_run;
  #pragma unroll
  for (int nt = 0; nt < 4; ++nt)
    #pragma unroll
    for (int r = 0; r < 4; ++r)
      Om[w][q_*4 + r][nt*16 + li] = oa[nt][r];
  __syncthreads();
  int qq = t >> 4, c4 = (t & 15) * 4;
  float m0 = ml[0][0][qq], m1 = ml[1][0][qq], m2 = ml[2][0][qq], m3 = ml[3][0][qq];
  float ms = fmaxf(fmaxf(m0, m1), fmaxf(m2, m3));
  float s0 = __expf(m0 - ms), s1 = __expf(m1 - ms);
  float s2 = __expf(m2 - ms), s3 = __expf(m3 - ms);
  float lt = ml[0][1][qq]*s0 + ml[1][1][qq]*s1 + ml[2][1][qq]*s2 + ml[3][1][qq]*s3;
  float inv = 1.f / lt;
  float sw[4] = {s0, s1, s2, s3};
  float4v o = {0.f, 0.f, 0.f, 0.f};
  #pragma unroll
  for (int w2 = 0; w2 < 4; ++w2) {
    float4v ov = *(const float4v*)(&Om[w2][qq][c4]);
    #pragma unroll
    for (int r = 0; r < 4; ++r) o[r] += ov[r] * sw[w2];
  }
  float4v outv;
  #pragma unroll
  for (int r = 0; r < 4; ++r) outv[r] = o[r] * inv;
  *(float4v*)(hgt + (size_t)batch*NCELL*64 + (size_t)(i0 + qq)*64 + c4) = outv;
}

// ---------------- K6: per-chunk 0.75*hp~ MFMA + one-shot stream epilogue ----
// Publish all 64 channel-rows as bf16 into fsb[64][204] (unioned with vch),
// then one uninterrupted 64x49-float4 stream. 3 barriers total.
__global__ __launch_bounds__(256) void k6_hp_out(
    const short* __restrict__ vtld, const short* __restrict__ P,
    const float* __restrict__ hgt,
    const float* __restrict__ x, float* __restrict__ out) {
  __shared__ __attribute__((aligned(16))) short smem[64*232];   // 29,696 B union
  short* vch = smem;                  // [c][p] pitch 232 (conflict-free b128)
  short* fsb = smem;                  // [64][204] bf16 out-stage (26,112 B)
  int bx = blockIdx.x;
  int batch = bx >> 10;
  int chunk = bx & 1023;
  int t = threadIdx.x;
  const short* vsrc = vtld + (size_t)batch*64*HW + chunk*P2;
  for (int idx = t; idx < 3136; idx += 256) {       // 64 rows x 49 short4
    int c = idx / 49, po = idx % 49;
    *(short4v*)(vch + c*232 + po*4) = *(const short4v*)(vsrc + (size_t)c*HW + po*4);
  }
  for (int idx = t; idx < 448; idx += 256) {        // zero pad cols 196..223
    int c = idx / 7, po = idx % 7;
    *(short4v*)(vch + c*232 + 196 + po*4) = (short4v){0,0,0,0};
  }
  __syncthreads();
  int l = t & 63, w = t >> 6, li = l & 15, q_ = l >> 4;
  int nt0 = w ? 4 + (w-1)*3 : 0;
  int ncnt = w ? 3 : 4;
  const short* Pb = P + (size_t)batch*208*224;
  ffrag acc[4][4];
  #pragma unroll
  for (int i = 0; i < 4; ++i)
    #pragma unroll
    for (int j = 0; j < 4; ++j) acc[i][j] = (ffrag){0.f,0.f,0.f,0.f};
  #pragma unroll
  for (int ks = 0; ks < 7; ++ks) {
    int koff = ks*32 + q_*8;
    bfrag av[4];
    #pragma unroll
    for (int mt = 0; mt < 4; ++mt) av[mt] = *(const bfrag*)(vch + (mt*16 + li)*232 + koff);
    #pragma unroll
    for (int ni = 0; ni < 4; ++ni) if (ni < ncnt) {
      bfrag bp = *(const bfrag*)(Pb + (size_t)((nt0+ni)*16 + li)*224 + koff);
      #pragma unroll
      for (int mt = 0; mt < 4; ++mt) acc[mt][ni] = MFMA16(av[mt], bp, acc[mt][ni]);
    }
  }
  __syncthreads();        // all vch reads done; fsb may overwrite the union
  // publish 0.75*hp (factor folded into P) as bf16, all 64 rows
  #pragma unroll
  for (int ni = 0; ni < 4; ++ni) if (ni < ncnt) {
    int pp = (nt0+ni)*16 + li;
    if (pp < 196) {
      #pragma unroll
      for (int mt = 0; mt < 4; ++mt)
        #pragma unroll
        for (int r = 0; r < 4; ++r)
          fsb[(mt*16 + q_*4 + r)*204 + pp] = f2bf(acc[mt][ni][r]);
    }
  }
  __syncthreads();
  // one-shot stream: out = x + fs + 0.25*hg over 64x49 float4 rows
  const float* hgb = hgt + (size_t)batch*NCELL*64;
  const float* xb = x + (size_t)batch*CHW;
  float* ob = out + (size_t)batch*CHW;
  int gbase = chunk*P2;
  for (int idx = t; idx < 3136; idx += 256) {
    int c = idx / 49, po = idx % 49;
    int g = gbase + po*4;                // 4 px of a float4 share one pool cell
    int cell = ((g/448) >> 3)*56 + ((g%448) >> 3);
    float hr = 0.25f * hgb[cell*64 + c];
    size_t off = (size_t)c*HW + (size_t)gbase + po*4;
    float4v xv = *(const float4v*)(xb + off);
    short4v fb = *(const short4v*)(fsb + c*204 + po*4);
    float4v o;
    #pragma unroll
    for (int r = 0; r < 4; ++r) {
      float fv = __builtin_bit_cast(float, ((unsigned)(unsigned short)fb[r]) << 16);
      o[r] = xv[r] + fv + hr;
    }
    *(float4v*)(ob + off) = o;
  }
}

// ---------------- launch ----------------------------------------------------
extern "C" void kernel_launch(void* const* d_in, const int* in_sizes, int n_in,
                              void* d_out, int out_size, void* d_ws, size_t ws_size,
                              hipStream_t stream) {
  (void)in_sizes; (void)n_in; (void)out_size; (void)ws_size;
  const float* x   = (const float*)d_in[0];
  const float* gnw = (const float*)d_in[1];
  const float* gnb = (const float*)d_in[2];
  const float* qw  = (const float*)d_in[3];
  const float* qb  = (const float*)d_in[4];
  const float* kw  = (const float*)d_in[5];
  const float* kb  = (const float*)d_in[6];
  const float* vw  = (const float*)d_in[7];
  const float* vb  = (const float*)d_in[8];
  const float* pw  = (const float*)d_in[9];
  float* out = (float*)d_out;
  char* ws = (char*)d_ws;

  // ws layout (bytes), all 256-aligned; total ~160.3 MB
  short* qx    = (short*)(ws + 0);            // 51,380,224  q pixel-major bf16
  short* kx    = (short*)(ws + 51380224);     // 51,380,224
  short* vnat  = (short*)(ws + 102760448);    // 51,380,224  v~ c-major bf16
  float* xpool = (float*)(ws + 154140672);    //  1,605,632
  short* qgt   = (short*)(ws + 155746304);    //    802,816
  short* kgt   = (short*)(ws + 156549120);    //    802,816
  short* vgn   = (short*)(ws + 157351936);    //    802,816
  float* hgt   = (float*)(ws + 158154752);    //  1,605,632
  short* P     = (short*)(ws + 159760384);    //    186,368  [b][208][224] bf16
  float* wmacc = (float*)(ws + 159946752);    //    307,328  fp32 atomics
  float* stats = (float*)(ws + 160254080);    //         16
  // stats partials overlaid on P (7168*2*4 = 57,344 B); k1 writes, k1b reads,
  // then k4 overwrites P later -- no lifetime conflict.
  float* partials = (float*)(ws + 159760384);
  // folded V weights + GN-folded bf16 weights overlaid on hgt (first ~84 KB);
  // k0/k0b write, k2/k2a read, k5 overwrites hgt afterwards -- no conflict.
  float* wtld = (float*)(ws + 158154752);            // 16,384
  float* btld = (float*)(ws + 158154752 + 16384);    //    256
  short* qwb  = (short*)(ws + 158154752 + 32768);    // 16,384 (2 batches)
  short* kwb  = (short*)(ws + 158154752 + 49152);    // 16,384
  short* vwb  = (short*)(ws + 158154752 + 65536);    // 16,384
  float* qbb  = (float*)(ws + 158154752 + 81920);    //    512
  float* kbb  = (float*)(ws + 158154752 + 82432);    //    512
  float* vbb  = (float*)(ws + 158154752 + 82944);    //    512

  hipMemsetAsync(ws + 159946752, 0, 307328, stream);   // wmacc only
  k0_fold      <<<dim3(2),        dim3(256), 0, stream>>>(pw, vw, vb, wtld, btld);
  k1_stats_pool<<<dim3(NB*64*56), dim3(64),  0, stream>>>(x, xpool, partials);
  k1b_reduce   <<<dim3(1),        dim3(256), 0, stream>>>(partials, stats);
  k0b_foldgn   <<<dim3(NB),       dim3(256), 0, stream>>>(stats, gnw, gnb, qw, qb, kw, kb, wtld, btld, qwb, kwb, vwb, qbb, kbb, vbb);
  k2_qkv       <<<dim3(NB*784),   dim3(256), 0, stream>>>(x, qwb, kwb, vwb, qbb, kbb, vbb, qx, kx, vnat);
  k2a_pool_qkv <<<dim3(NB*49),    dim3(256), 0, stream>>>(xpool, stats, gnw, gnb, qw, qb, kw, kb, wtld, btld, qgt, kgt, vgn);
  k3_wm        <<<dim3(NB*512),   dim3(256), 0, stream>>>(qx, kx, wmacc);
  k4_softmax   <<<dim3(NB*208),   dim3(64),  0, stream>>>(wmacc, P);
  k5_gattn     <<<dim3(NB*196),   dim3(256), 0, stream>>>(qgt, kgt, vgn, hgt);
  k6_hp_out    <<<dim3(NB*1024),  dim3(256), 0, stream>>>(vnat, P, hgt, x, out);
}

// Round 11
// 577.059 us; speedup vs baseline: 1.0046x; 1.0046x over previous
//
#include <hip/hip_runtime.h>

// Problem constants
#define NB 2
#define NC 64
#define HW 200704          // 448*448
#define CHW 12845056       // 64*HW
#define P2 196
#define NCHUNK 1024
#define NCELL 3136         // 56*56
#define WMN 38416          // 196*196

typedef __attribute__((ext_vector_type(8))) short bfrag;   // 8 bf16 (A/B frag)
typedef __attribute__((ext_vector_type(4))) float ffrag;   // 4 f32  (C/D frag)
typedef __attribute__((ext_vector_type(4))) short short4v;
typedef __attribute__((ext_vector_type(4))) float float4v;

#define MFMA16(A,B,C) __builtin_amdgcn_mfma_f32_16x16x32_bf16(A,B,C,0,0,0)

__device__ __forceinline__ short f2bf(float f) {
  unsigned u = __builtin_bit_cast(unsigned, f);
  u = u + 0x7FFFu + ((u >> 16) & 1u);           // RNE
  return (short)(u >> 16);
}

// ---------------- K0: fold proj into V weights (linearity) ------------------
// wtld[o][c] = sum_m pw[o][m]*vw[m][c];  btld[o] = sum_m pw[o][m]*vb[m].
__global__ __launch_bounds__(256) void k0_fold(
    const float* __restrict__ pw, const float* __restrict__ vw,
    const float* __restrict__ vb, float* __restrict__ wtld, float* __restrict__ btld) {
  int t = threadIdx.x;
  if (blockIdx.x == 0) {
    #pragma unroll
    for (int i = 0; i < 16; ++i) {
      int idx = i*256 + t;
      int o = idx >> 6, c = idx & 63;
      float s = 0.f;
      for (int m = 0; m < 64; ++m) s += pw[o*64 + m] * vw[m*64 + c];
      wtld[o*64 + c] = s;
    }
  } else {
    if (t < 64) {
      float s = 0.f;
      for (int m = 0; m < 64; ++m) s += pw[t*64 + m] * vb[m];
      btld[t] = s;
    }
  }
}

// ---------------- K1: groupnorm partial stats + 8x8 avg-pool of x ----------
__global__ __launch_bounds__(64) void k1_stats_pool(
    const float* __restrict__ x, float* __restrict__ xpool, float* __restrict__ partials) {
  int bx = blockIdx.x;
  int batch = bx / (64*56);
  int c = (bx / 56) % 64;
  int pr = bx % 56;
  int l = threadIdx.x;
  const float* xp = x + (size_t)batch*CHW + (size_t)c*HW + pr*8*448;
  float cell = 0.f, s2 = 0.f;
  if (l < 56) {
    #pragma unroll
    for (int r = 0; r < 8; ++r) {
      float4v a = *(const float4v*)(xp + r*448 + l*8);
      float4v b = *(const float4v*)(xp + r*448 + l*8 + 4);
      #pragma unroll
      for (int j = 0; j < 4; ++j) { cell += a[j] + b[j]; s2 += a[j]*a[j] + b[j]*b[j]; }
    }
    xpool[((size_t)batch*64 + c)*NCELL + pr*56 + l] = cell * (1.f/64.f);
  }
  float s1 = (l < 56) ? cell : 0.f;
  #pragma unroll
  for (int m = 1; m < 64; m <<= 1) { s1 += __shfl_xor(s1, m, 64); s2 += __shfl_xor(s2, m, 64); }
  if (l == 0) { partials[bx*2] = s1; partials[bx*2 + 1] = s2; }
}

// ---------------- K1b: reduce 7168 partial pairs -> stats[4] ---------------
__global__ __launch_bounds__(256) void k1b_reduce(
    const float* __restrict__ partials, float* __restrict__ stats) {
  __shared__ float red[2][256];
  int t = threadIdx.x;
  for (int b = 0; b < NB; ++b) {
    float s1 = 0.f, s2 = 0.f;
    for (int i = t; i < 3584; i += 256) {
      s1 += partials[(b*3584 + i)*2];
      s2 += partials[(b*3584 + i)*2 + 1];
    }
    red[0][t] = s1; red[1][t] = s2;
    __syncthreads();
    for (int m = 128; m > 0; m >>= 1) {
      if (t < m) { red[0][t] += red[0][t+m]; red[1][t] += red[1][t+m]; }
      __syncthreads();
    }
    if (t == 0) { stats[b*2] = red[0][0]; stats[b*2+1] = red[1][0]; }
    __syncthreads();
  }
}

// ---------------- K0b: fold GN affine into bf16 weights (per batch) --------
// xn_c = a_c x_c + d_c with a_c = rstd*gnw_c, d_c = gnb_c - mean*a_c.
// W' = W*diag(a) (bf16), b' = b + W.d (fp32). grid NB x 256.
__global__ __launch_bounds__(256) void k0b_foldgn(
    const float* __restrict__ stats, const float* __restrict__ gnw, const float* __restrict__ gnb,
    const float* __restrict__ qw, const float* __restrict__ qb,
    const float* __restrict__ kw, const float* __restrict__ kb,
    const float* __restrict__ vw, const float* __restrict__ vb,
    short* __restrict__ qwb, short* __restrict__ kwb, short* __restrict__ vwb,
    float* __restrict__ qbb, float* __restrict__ kbb, float* __restrict__ vbb) {
  __shared__ float a_s[64], d_s[64];
  int batch = blockIdx.x;
  int t = threadIdx.x;
  float s1 = stats[batch*2], s2 = stats[batch*2+1];
  float mean = s1 * (1.f/CHW);
  float rstd = rsqrtf(s2*(1.f/CHW) - mean*mean + 1e-5f);
  if (t < 64) { float a = rstd*gnw[t]; a_s[t] = a; d_s[t] = gnb[t] - mean*a; }
  __syncthreads();
  const float* Ws[3] = {qw, kw, vw};
  const float* Bs[3] = {qb, kb, vb};
  short* Wo[3] = {qwb, kwb, vwb};
  float* Bo[3] = {qbb, kbb, vbb};
  for (int T = 0; T < 3; ++T) {
    #pragma unroll
    for (int i = 0; i < 16; ++i) {
      int idx = i*256 + t;
      int c = idx & 63;
      Wo[T][batch*4096 + idx] = f2bf(Ws[T][idx] * a_s[c]);
    }
    if (t < 64) {
      float s = Bs[T][t];
      for (int c = 0; c < 64; ++c) s += Ws[T][t*64 + c] * d_s[c];
      Bo[T][batch*64 + t] = s;
    }
  }
}

// ---------------- K2: q,k,v~ = W'.x (GN pre-folded, bf16 weights) ----------
__global__ __launch_bounds__(256) void k2_qkv(
    const float* __restrict__ x,
    const short* __restrict__ qwb, const short* __restrict__ kwb, const short* __restrict__ vwb,
    const float* __restrict__ qbb, const float* __restrict__ kbb, const float* __restrict__ vbb,
    short* __restrict__ qx, short* __restrict__ kx, short* __restrict__ vnat) {
  __shared__ __attribute__((aligned(16))) short xnt[256*72];  // [px][c] bf16, pitch 72
  int bx = blockIdx.x;
  int batch = bx / 784;
  int px0 = (bx % 784) * 256;
  int t = threadIdx.x;
  for (int it = 0; it < 64; it += 4) {
    short4v s;
    #pragma unroll
    for (int r = 0; r < 4; ++r)
      s[r] = f2bf(x[(size_t)batch*CHW + (size_t)(it+r)*HW + px0 + t]);
    *(short4v*)(xnt + t*72 + it) = s;
  }
  __syncthreads();
  int l = t & 63, w = t >> 6, li = l & 15, q_ = l >> 4;
  bfrag bfr[4][2];
  #pragma unroll
  for (int nn = 0; nn < 4; ++nn) {
    int row = (w*4 + nn)*16 + li;
    bfr[nn][0] = *(const bfrag*)(xnt + row*72 + q_*8);
    bfr[nn][1] = *(const bfrag*)(xnt + row*72 + 32 + q_*8);
  }
  const short* Wb[3] = {qwb + batch*4096, kwb + batch*4096, vwb + batch*4096};
  const float* Bb[3] = {qbb + batch*64, kbb + batch*64, vbb + batch*64};
  for (int T = 0; T < 3; ++T) {
    ffrag acc[4][4];
    #pragma unroll
    for (int mt = 0; mt < 4; ++mt) {
      bfrag aw0 = *(const bfrag*)(Wb[T] + (mt*16 + li)*64 + q_*8);
      bfrag aw1 = *(const bfrag*)(Wb[T] + (mt*16 + li)*64 + 32 + q_*8);
      #pragma unroll
      for (int nn = 0; nn < 4; ++nn) {
        ffrag z = {0.f,0.f,0.f,0.f};
        if (T < 2) {            // C[o][px]: col(li)=px, row(q_*4+r)=channel
          z = MFMA16(aw0, bfr[nn][0], z);
          z = MFMA16(aw1, bfr[nn][1], z);
        } else {                // swapped -> C[px][o]: col(li)=channel, rows=px
          z = MFMA16(bfr[nn][0], aw0, z);
          z = MFMA16(bfr[nn][1], aw1, z);
        }
        acc[mt][nn] = z;
      }
    }
    if (T < 2) {
      short* dstb = (T == 0 ? qx : kx) + (size_t)batch*HW*64;
      #pragma unroll
      for (int nn = 0; nn < 4; ++nn) {
        int px = px0 + (w*4 + nn)*16 + li;
        #pragma unroll
        for (int mt = 0; mt < 4; ++mt) {
          float4v bias = *(const float4v*)(Bb[T] + mt*16 + q_*4);
          short4v s;
          #pragma unroll
          for (int r = 0; r < 4; ++r) s[r] = f2bf(acc[mt][nn][r] + bias[r]);
          *(short4v*)(dstb + (size_t)px*64 + mt*16 + q_*4) = s;
        }
      }
    } else {
      #pragma unroll
      for (int mt = 0; mt < 4; ++mt) {
        float bias = Bb[2][mt*16 + li];        // channel = mt*16+li
        short* vrow = vnat + ((size_t)batch*64 + mt*16 + li)*HW + px0;
        #pragma unroll
        for (int nn = 0; nn < 4; ++nn) {
          short4v s;
          #pragma unroll
          for (int r = 0; r < 4; ++r) s[r] = f2bf(acc[mt][nn][r] + bias);
          *(short4v*)(vrow + (w*4 + nn)*16 + q_*4) = s;
        }
      }
    }
  }
}

// ---------------- K2a: pooled qg/kg/vg~ from pool(x) (linearity) -----------
__global__ __launch_bounds__(256) void k2a_pool_qkv(
    const float* __restrict__ xpool, const float* __restrict__ stats,
    const float* __restrict__ gnw, const float* __restrict__ gnb,
    const float* __restrict__ qw, const float* __restrict__ qb,
    const float* __restrict__ kw, const float* __restrict__ kb,
    const float* __restrict__ vw, const float* __restrict__ vb,
    short* __restrict__ qgt, short* __restrict__ kgt, short* __restrict__ vgn) {
  __shared__ float xs[64][64];
  int bx = blockIdx.x;
  int batch = bx / 49;
  int j0 = (bx % 49) * 64;
  int t = threadIdx.x;
  float s1 = stats[batch*2], s2 = stats[batch*2+1];
  float mean = s1 * (1.f/CHW);
  float rstd = rsqrtf(s2*(1.f/CHW) - mean*mean + 1e-5f);
  #pragma unroll
  for (int it = 0; it < 16; ++it) {
    int idx = t + it*256;
    int c = idx >> 6, jl = idx & 63;
    float v = xpool[((size_t)batch*64 + c)*NCELL + j0 + jl];
    xs[c][jl] = (v - mean)*rstd*gnw[c] + gnb[c];
  }
  __syncthreads();
  int jl = t & 63;
  int og = (t >> 6) * 16;
  int j = j0 + jl;
  for (int T = 0; T < 3; ++T) {
    const float* W  = (T==0 ? qw : (T==1 ? kw : vw));
    const float* Bv = (T==0 ? qb : (T==1 ? kb : vb));
    float o16[16];
    #pragma unroll
    for (int oo = 0; oo < 16; ++oo) o16[oo] = Bv[og+oo];
    for (int c = 0; c < 64; ++c) {
      float xv = xs[c][jl];
      #pragma unroll
      for (int oo = 0; oo < 16; ++oo) o16[oo] += W[(og+oo)*64 + c] * xv;
    }
    if (T < 2) {
      short* dst = (T==0 ? qgt : kgt) + ((size_t)batch*NCELL + j)*64 + og;
      #pragma unroll
      for (int oo = 0; oo < 16; oo += 4) {
        short4v s;
        #pragma unroll
        for (int r = 0; r < 4; ++r) s[r] = f2bf(o16[oo+r]);
        *(short4v*)(dst + oo) = s;
      }
    } else {
      #pragma unroll
      for (int oo = 0; oo < 16; ++oo)
        vgn[((size_t)batch*64 + og + oo)*NCELL + j] = f2bf(o16[oo]);
    }
  }
}

// ---------------- K3: wm[p,q] = sum_s qf[s,p] kf[s,q] ----------------------
// R11: R9 geometry (64 slabs x 4 n-quarters = 512 blocks; FETCH 128MB) +
// R10's register double-buffer pipelining (one load batch in flight under
// every MFMA batch). R10's 8-way split raised FETCH 128->214MB (+36us of
// traffic) and ate the occupancy gain -- traffic, not block count, is k3's
// binding constraint. Atomic count unchanged (64 slab-adds/element).
__global__ __launch_bounds__(256) void k3_wm(
    const short* __restrict__ qx, const short* __restrict__ kx, float* __restrict__ wmacc) {
  int bx = blockIdx.x;
  int batch = bx >> 8;
  int rem = bx & 255;
  int slab = rem >> 2;
  int qd = rem & 3;
  int t = threadIdx.x;
  int l = t & 63, w = t >> 6, li = l & 15, q_ = l >> 4;
  int m0 = w ? 4 + (w-1)*3 : 0, mcnt = w ? 3 : 4;
  int nt0 = qd ? 4 + (qd-1)*3 : 0, ncnt = qd ? 3 : 4;
  ffrag acc[4][4];
  #pragma unroll
  for (int i = 0; i < 4; ++i)
    #pragma unroll
    for (int j = 0; j < 4; ++j) acc[i][j] = (ffrag){0.f,0.f,0.f,0.f};
  const short* qbase = qx + ((size_t)batch*HW + (size_t)slab*16*P2)*64;
  const short* kbase = kx + ((size_t)batch*HW + (size_t)slab*16*P2)*64;
  bfrag afA[4], bfA[4], afB[4], bfB[4];
  auto ld = [&](int s, bfrag* af, bfrag* bf) {
    int c8 = s >> 1;
    int koff = (s & 1)*32 + q_*8;
    const short* qc = qbase + (size_t)c8*P2*64;
    const short* kc = kbase + (size_t)c8*P2*64;
    #pragma unroll
    for (int mi = 0; mi < 4; ++mi) if (mi < mcnt)
      af[mi] = *(const bfrag*)(qc + (size_t)((m0+mi)*16 + li)*64 + koff);
    #pragma unroll
    for (int ni = 0; ni < 4; ++ni) if (ni < ncnt)
      bf[ni] = *(const bfrag*)(kc + (size_t)((nt0+ni)*16 + li)*64 + koff);
  };
  auto mm = [&](bfrag* af, bfrag* bf) {
    #pragma unroll
    for (int mi = 0; mi < 4; ++mi) if (mi < mcnt)
      #pragma unroll
      for (int ni = 0; ni < 4; ++ni) if (ni < ncnt)
        acc[mi][ni] = MFMA16(af[mi], bf[ni], acc[mi][ni]);
  };
  // 32 (chunk,ks)-steps, software-pipelined with A/B register buffers
  ld(0, afA, bfA);
  for (int s = 0; s < 32; s += 2) {
    ld(s+1, afB, bfB);
    mm(afA, bfA);
    if (s+2 < 32) ld(s+2, afA, bfA);
    mm(afB, bfB);
  }
  float* wdst = wmacc + (size_t)batch*WMN;
  #pragma unroll
  for (int mi = 0; mi < 4; ++mi) if (mi < mcnt)
    #pragma unroll
    for (int ni = 0; ni < 4; ++ni) if (ni < ncnt) {
      int qcol = (nt0+ni)*16 + li;
      if (qcol < 196)
        #pragma unroll
        for (int r = 0; r < 4; ++r) {
          int prow = (m0+mi)*16 + q_*4 + r;
          if (prow < 196) atomicAdd(wdst + prow*196 + qcol, acc[mi][ni][r]);
        }
    }
}

// ---------------- K4: scale + softmax rows -> P bf16 [208][224] zero-padded -
// 0.75 hp-combine factor folded into P (inv *= 0.75).
__global__ __launch_bounds__(64) void k4_softmax(
    const float* __restrict__ wmacc, short* __restrict__ P) {
  int bx = blockIdx.x;         // NB*208
  int batch = bx / 208;
  int p = bx % 208;
  int l = threadIdx.x;
  short* prow = P + ((size_t)batch*208 + p)*224;
  if (p >= 196) { for (int j = l; j < 224; j += 64) prow[j] = 0; return; }
  const float* src = wmacc + (size_t)batch*WMN + p*196;
  float v[4]; float mx = -1e30f;
  #pragma unroll
  for (int i = 0; i < 4; ++i) {
    int q = l + i*64;
    v[i] = (q < 196) ? src[q]*(1.f/256.f) : -1e30f;
    mx = fmaxf(mx, v[i]);
  }
  #pragma unroll
  for (int m = 1; m < 64; m <<= 1) mx = fmaxf(mx, __shfl_xor(mx, m, 64));
  float s = 0.f;
  #pragma unroll
  for (int i = 0; i < 4; ++i) { v[i] = __expf(v[i] - mx); s += v[i]; }
  #pragma unroll
  for (int m = 1; m < 64; m <<= 1) s += __shfl_xor(s, m, 64);
  float inv = 0.75f / s;        // fold hp combine weight into P
  #pragma unroll
  for (int i = 0; i < 4; ++i) {
    int q = l + i*64;
    if (q < 224) prow[q] = (q < 196) ? f2bf(v[i]*inv) : (short)0;
  }
}

// ---------------- K5: global pooled attention, flash-style ------------------
// grid NB*196: block = one 16-query tile; 4 waves split the 49 KV tiles with
// private (m,l,O), no intra-loop barriers; final 256-thread merge.
__global__ __launch_bounds__(256) void k5_gattn(
    const short* __restrict__ qgt, const short* __restrict__ kgt,
    const short* __restrict__ vgn, float* __restrict__ hgt) {
  __shared__ __attribute__((aligned(16))) short Pl[4][16][72];
  __shared__ __attribute__((aligned(16))) float alph[4][16];
  __shared__ __attribute__((aligned(16))) float Om[4][16][64];
  __shared__ __attribute__((aligned(16))) float ml[4][2][16];
  int bx = blockIdx.x;
  int batch = bx / 196;
  int i0 = (bx % 196) * 16;
  int t = threadIdx.x;
  int w = t >> 6, l = t & 63, li = l & 15, q_ = l >> 4;
  const short* qg = qgt + (size_t)batch*NCELL*64;
  const short* kg = kgt + (size_t)batch*NCELL*64;
  const short* vg = vgn + (size_t)batch*64*NCELL;
  bfrag bq0 = *(const bfrag*)(qg + (size_t)(i0+li)*64 + q_*8);
  bfrag bq1 = *(const bfrag*)(qg + (size_t)(i0+li)*64 + 32 + q_*8);
  float m_run = -1e30f, l_run = 0.f;
  ffrag oa[4];
  #pragma unroll
  for (int i = 0; i < 4; ++i) oa[i] = (ffrag){0.f,0.f,0.f,0.f};
  for (int jt = w; jt < 49; jt += 4) {
    int j0 = jt*64;
    ffrag st[4];
    #pragma unroll
    for (int mt = 0; mt < 4; ++mt) {        // S^T[j,i]: rows j, cols i
      bfrag a0 = *(const bfrag*)(kg + (size_t)(j0 + mt*16 + li)*64 + q_*8);
      bfrag a1 = *(const bfrag*)(kg + (size_t)(j0 + mt*16 + li)*64 + 32 + q_*8);
      ffrag z = {0.f,0.f,0.f,0.f};
      z = MFMA16(a0, bq0, z);
      z = MFMA16(a1, bq1, z);
      st[mt] = z;
    }
    float mx = -1e30f;
    #pragma unroll
    for (int mt = 0; mt < 4; ++mt)
      #pragma unroll
      for (int r = 0; r < 4; ++r) { st[mt][r] *= 0.125f; mx = fmaxf(mx, st[mt][r]); }
    mx = fmaxf(mx, __shfl_xor(mx, 16, 64));
    mx = fmaxf(mx, __shfl_xor(mx, 32, 64));
    float m_new = fmaxf(m_run, mx);
    float alpha = __expf(m_run - m_new);
    float ps = 0.f;
    short4v pk[4];
    #pragma unroll
    for (int mt = 0; mt < 4; ++mt)
      #pragma unroll
      for (int r = 0; r < 4; ++r) { float e = __expf(st[mt][r] - m_new); ps += e; pk[mt][r] = f2bf(e); }
    ps += __shfl_xor(ps, 16, 64);
    ps += __shfl_xor(ps, 32, 64);
    l_run = l_run*alpha + ps;
    m_run = m_new;
    #pragma unroll
    for (int mt = 0; mt < 4; ++mt) *(short4v*)(&Pl[w][li][mt*16 + q_*4]) = pk[mt];
    alph[w][li] = alpha;
    // no barrier: wave reads only its own Pl[w]/alph[w]
    float4v al = *(const float4v*)(&alph[w][q_*4]);
    #pragma unroll
    for (int nt = 0; nt < 4; ++nt)
      #pragma unroll
      for (int r = 0; r < 4; ++r) oa[nt][r] *= al[r];
    #pragma unroll
    for (int ks = 0; ks < 2; ++ks) {
      bfrag a = *(const bfrag*)(&Pl[w][li][ks*32 + q_*8]);
      #pragma unroll
      for (int nt = 0; nt < 4; ++nt) {
        bfrag b = *(const bfrag*)(vg + (size_t)(nt*16 + li)*NCELL + j0 + ks*32 + q_*8);
        oa[nt] = MFMA16(a, b, oa[nt]);
      }
    }
  }
  ml[w][0][li] = m_run;
  ml[w][1][li] = l_run;
  #pragma unroll
  for (int nt = 0; nt < 4; ++nt)
    #pragma unroll
    for (int r = 0; r < 4; ++r)
      Om[w][q_*4 + r][nt*16 + li] = oa[nt][r];
  __syncthreads();
  int qq = t >> 4, c4 = (t & 15) * 4;
  float m0 = ml[0][0][qq], m1 = ml[1][0][qq], m2 = ml[2][0][qq], m3 = ml[3][0][qq];
  float ms = fmaxf(fmaxf(m0, m1), fmaxf(m2, m3));
  float s0 = __expf(m0 - ms), s1 = __expf(m1 - ms);
  float s2 = __expf(m2 - ms), s3 = __expf(m3 - ms);
  float lt = ml[0][1][qq]*s0 + ml[1][1][qq]*s1 + ml[2][1][qq]*s2 + ml[3][1][qq]*s3;
  float inv = 1.f / lt;
  float sw[4] = {s0, s1, s2, s3};
  float4v o = {0.f, 0.f, 0.f, 0.f};
  #pragma unroll
  for (int w2 = 0; w2 < 4; ++w2) {
    float4v ov = *(const float4v*)(&Om[w2][qq][c4]);
    #pragma unroll
    for (int r = 0; r < 4; ++r) o[r] += ov[r] * sw[w2];
  }
  float4v outv;
  #pragma unroll
  for (int r = 0; r < 4; ++r) outv[r] = o[r] * inv;
  *(float4v*)(hgt + (size_t)batch*NCELL*64 + (size_t)(i0 + qq)*64 + c4) = outv;
}

// ---------------- K6: per-chunk 0.75*hp~ MFMA + one-shot stream epilogue ----
// Publish all 64 channel-rows as bf16 into fsb[64][204] (unioned with vch),
// then one uninterrupted 64x49-float4 stream. 3 barriers total.
__global__ __launch_bounds__(256) void k6_hp_out(
    const short* __restrict__ vtld, const short* __restrict__ P,
    const float* __restrict__ hgt,
    const float* __restrict__ x, float* __restrict__ out) {
  __shared__ __attribute__((aligned(16))) short smem[64*232];   // 29,696 B union
  short* vch = smem;                  // [c][p] pitch 232 (conflict-free b128)
  short* fsb = smem;                  // [64][204] bf16 out-stage (26,112 B)
  int bx = blockIdx.x;
  int batch = bx >> 10;
  int chunk = bx & 1023;
  int t = threadIdx.x;
  const short* vsrc = vtld + (size_t)batch*64*HW + chunk*P2;
  for (int idx = t; idx < 3136; idx += 256) {       // 64 rows x 49 short4
    int c = idx / 49, po = idx % 49;
    *(short4v*)(vch + c*232 + po*4) = *(const short4v*)(vsrc + (size_t)c*HW + po*4);
  }
  for (int idx = t; idx < 448; idx += 256) {        // zero pad cols 196..223
    int c = idx / 7, po = idx % 7;
    *(short4v*)(vch + c*232 + 196 + po*4) = (short4v){0,0,0,0};
  }
  __syncthreads();
  int l = t & 63, w = t >> 6, li = l & 15, q_ = l >> 4;
  int nt0 = w ? 4 + (w-1)*3 : 0;
  int ncnt = w ? 3 : 4;
  const short* Pb = P + (size_t)batch*208*224;
  ffrag acc[4][4];
  #pragma unroll
  for (int i = 0; i < 4; ++i)
    #pragma unroll
    for (int j = 0; j < 4; ++j) acc[i][j] = (ffrag){0.f,0.f,0.f,0.f};
  #pragma unroll
  for (int ks = 0; ks < 7; ++ks) {
    int koff = ks*32 + q_*8;
    bfrag av[4];
    #pragma unroll
    for (int mt = 0; mt < 4; ++mt) av[mt] = *(const bfrag*)(vch + (mt*16 + li)*232 + koff);
    #pragma unroll
    for (int ni = 0; ni < 4; ++ni) if (ni < ncnt) {
      bfrag bp = *(const bfrag*)(Pb + (size_t)((nt0+ni)*16 + li)*224 + koff);
      #pragma unroll
      for (int mt = 0; mt < 4; ++mt) acc[mt][ni] = MFMA16(av[mt], bp, acc[mt][ni]);
    }
  }
  __syncthreads();        // all vch reads done; fsb may overwrite the union
  // publish 0.75*hp (factor folded into P) as bf16, all 64 rows
  #pragma unroll
  for (int ni = 0; ni < 4; ++ni) if (ni < ncnt) {
    int pp = (nt0+ni)*16 + li;
    if (pp < 196) {
      #pragma unroll
      for (int mt = 0; mt < 4; ++mt)
        #pragma unroll
        for (int r = 0; r < 4; ++r)
          fsb[(mt*16 + q_*4 + r)*204 + pp] = f2bf(acc[mt][ni][r]);
    }
  }
  __syncthreads();
  // one-shot stream: out = x + fs + 0.25*hg over 64x49 float4 rows
  const float* hgb = hgt + (size_t)batch*NCELL*64;
  const float* xb = x + (size_t)batch*CHW;
  float* ob = out + (size_t)batch*CHW;
  int gbase = chunk*P2;
  for (int idx = t; idx < 3136; idx += 256) {
    int c = idx / 49, po = idx % 49;
    int g = gbase + po*4;                // 4 px of a float4 share one pool cell
    int cell = ((g/448) >> 3)*56 + ((g%448) >> 3);
    float hr = 0.25f * hgb[cell*64 + c];
    size_t off = (size_t)c*HW + (size_t)gbase + po*4;
    float4v xv = *(const float4v*)(xb + off);
    short4v fb = *(const short4v*)(fsb + c*204 + po*4);
    float4v o;
    #pragma unroll
    for (int r = 0; r < 4; ++r) {
      float fv = __builtin_bit_cast(float, ((unsigned)(unsigned short)fb[r]) << 16);
      o[r] = xv[r] + fv + hr;
    }
    *(float4v*)(ob + off) = o;
  }
}

// ---------------- launch ----------------------------------------------------
extern "C" void kernel_launch(void* const* d_in, const int* in_sizes, int n_in,
                              void* d_out, int out_size, void* d_ws, size_t ws_size,
                              hipStream_t stream) {
  (void)in_sizes; (void)n_in; (void)out_size; (void)ws_size;
  const float* x   = (const float*)d_in[0];
  const float* gnw = (const float*)d_in[1];
  const float* gnb = (const float*)d_in[2];
  const float* qw  = (const float*)d_in[3];
  const float* qb  = (const float*)d_in[4];
  const float* kw  = (const float*)d_in[5];
  const float* kb  = (const float*)d_in[6];
  const float* vw  = (const float*)d_in[7];
  const float* vb  = (const float*)d_in[8];
  const float* pw  = (const float*)d_in[9];
  float* out = (float*)d_out;
  char* ws = (char*)d_ws;

  // ws layout (bytes), all 256-aligned; total ~160.3 MB
  short* qx    = (short*)(ws + 0);            // 51,380,224  q pixel-major bf16
  short* kx    = (short*)(ws + 51380224);     // 51,380,224
  short* vnat  = (short*)(ws + 102760448);    // 51,380,224  v~ c-major bf16
  float* xpool = (float*)(ws + 154140672);    //  1,605,632
  short* qgt   = (short*)(ws + 155746304);    //    802,816
  short* kgt   = (short*)(ws + 156549120);    //    802,816
  short* vgn   = (short*)(ws + 157351936);    //    802,816
  float* hgt   = (float*)(ws + 158154752);    //  1,605,632
  short* P     = (short*)(ws + 159760384);    //    186,368  [b][208][224] bf16
  float* wmacc = (float*)(ws + 159946752);    //    307,328  fp32 atomics
  float* stats = (float*)(ws + 160254080);    //         16
  // stats partials overlaid on P (7168*2*4 = 57,344 B); k1 writes, k1b reads,
  // then k4 overwrites P later -- no lifetime conflict.
  float* partials = (float*)(ws + 159760384);
  // folded V weights + GN-folded bf16 weights overlaid on hgt (first ~84 KB);
  // k0/k0b write, k2/k2a read, k5 overwrites hgt afterwards -- no conflict.
  float* wtld = (float*)(ws + 158154752);            // 16,384
  float* btld = (float*)(ws + 158154752 + 16384);    //    256
  short* qwb  = (short*)(ws + 158154752 + 32768);    // 16,384 (2 batches)
  short* kwb  = (short*)(ws + 158154752 + 49152);    // 16,384
  short* vwb  = (short*)(ws + 158154752 + 65536);    // 16,384
  float* qbb  = (float*)(ws + 158154752 + 81920);    //    512
  float* kbb  = (float*)(ws + 158154752 + 82432);    //    512
  float* vbb  = (float*)(ws + 158154752 + 82944);    //    512

  hipMemsetAsync(ws + 159946752, 0, 307328, stream);   // wmacc only
  k0_fold      <<<dim3(2),        dim3(256), 0, stream>>>(pw, vw, vb, wtld, btld);
  k1_stats_pool<<<dim3(NB*64*56), dim3(64),  0, stream>>>(x, xpool, partials);
  k1b_reduce   <<<dim3(1),        dim3(256), 0, stream>>>(partials, stats);
  k0b_foldgn   <<<dim3(NB),       dim3(256), 0, stream>>>(stats, gnw, gnb, qw, qb, kw, kb, wtld, btld, qwb, kwb, vwb, qbb, kbb, vbb);
  k2_qkv       <<<dim3(NB*784),   dim3(256), 0, stream>>>(x, qwb, kwb, vwb, qbb, kbb, vbb, qx, kx, vnat);
  k2a_pool_qkv <<<dim3(NB*49),    dim3(256), 0, stream>>>(xpool, stats, gnw, gnb, qw, qb, kw, kb, wtld, btld, qgt, kgt, vgn);
  k3_wm        <<<dim3(NB*256),   dim3(256), 0, stream>>>(qx, kx, wmacc);
  k4_softmax   <<<dim3(NB*208),   dim3(64),  0, stream>>>(wmacc, P);
  k5_gattn     <<<dim3(NB*196),   dim3(256), 0, stream>>>(qgt, kgt, vgn, hgt);
  k6_hp_out    <<<dim3(NB*1024),  dim3(256), 0, stream>>>(vnat, P, hgt, x, out);
}